// Round 9
// baseline (910.795 us; speedup 1.0000x reference)
//
#include <hip/hip_runtime.h>
#include <stdint.h>

#define NB 128   // batch
#define NT 512   // time steps
#define NI 256   // input dim
#define NH 512   // hidden dim
#define NO 256   // output dim

// ---------- bf16 helpers ----------
__device__ __forceinline__ uint16_t f2bf(float x) {
  uint32_t u = __float_as_uint(x);
  return (uint16_t)((u + 0x7fffu + ((u >> 16) & 1u)) >> 16);
}
__device__ __forceinline__ uint32_t pack2bf(float a, float b) {
  return (uint32_t)f2bf(a) | ((uint32_t)f2bf(b) << 16);
}

__device__ __forceinline__ float fast_tanh(float x) {
  float e = __expf(2.0f * x);
#if __has_builtin(__builtin_amdgcn_rcpf)
  return 1.0f - 2.0f * __builtin_amdgcn_rcpf(e + 1.0f);
#else
  return 1.0f - 2.0f / (e + 1.0f);
#endif
}

typedef __bf16 bf16x8 __attribute__((ext_vector_type(8)));
typedef float f32x4 __attribute__((ext_vector_type(4)));

__device__ __forceinline__ f32x4 mfma16(bf16x8 a, uint4 b, f32x4 c) {
  return __builtin_amdgcn_mfma_f32_16x16x32_bf16(a, __builtin_bit_cast(bf16x8, b), c, 0, 0, 0);
}
__device__ __forceinline__ f32x4 mfma16_ab(uint4 a, bf16x8 b, f32x4 c) {
  return __builtin_amdgcn_mfma_f32_16x16x32_bf16(__builtin_bit_cast(bf16x8, a), b, c, 0, 0, 0);
}

// ---------- kernel 0: pack W_hh B-frags; Wih->frag order; transpose W_out; bias sum ----------
// B-frag quad q = u*16 + tk (u=n-tile 0..3, tk=k-tile 0..15):
//   n = (t>>6)*64 + u*16 + (t&15), k = tk*32 + ((t>>4)&3)*8 + j, value W_hh[n][k].
// Stored WB[q*512 + t]. recur: q<56 -> AGPR-resident, q>=56 -> LDS (8 quads).
// xproj A-frag WihF[(U*8+k0)*64 + l]: row n=U*16+(l&15), k=k0*32+(l>>4)*8+j.
__global__ __launch_bounds__(256) void prep_kernel(const float* __restrict__ Whh,
                                                   const float* __restrict__ Wih,
                                                   const float* __restrict__ Wout,
                                                   const float* __restrict__ bih,
                                                   const float* __restrict__ bhh,
                                                   uint4* __restrict__ WB,
                                                   float* __restrict__ WoT,
                                                   uint4* __restrict__ WihF,
                                                   float* __restrict__ BS) {
  int idx = blockIdx.x * 256 + threadIdx.x;
  if (idx < 32768) {                       // W_hh B-fragments
    int q = idx >> 9, t = idx & 511;
    int u = q >> 4, tk = q & 15;
    int n = (t >> 6) * 64 + u * 16 + (t & 15);
    int kb = tk * 32 + ((t >> 4) & 3) * 8;
    const float* row = Whh + (size_t)n * NH + kb;
    float4 f0 = *(const float4*)row;
    float4 f1 = *(const float4*)(row + 4);
    uint4 wq;
    wq.x = pack2bf(f0.x, f0.y);
    wq.y = pack2bf(f0.z, f0.w);
    wq.z = pack2bf(f1.x, f1.y);
    wq.w = pack2bf(f1.z, f1.w);
    WB[idx] = wq;
  } else if (idx < 49152) {                // Wih A-fragments (for xproj arg0)
    int i = idx - 32768;
    int l = i & 63;
    int uk = i >> 6;
    int k0 = uk & 7, u = uk >> 3;
    int n = u * 16 + (l & 15);
    int kb = k0 * 32 + (l >> 4) * 8;
    const float* row = Wih + (size_t)n * NI + kb;
    float4 f0 = *(const float4*)row;
    float4 f1 = *(const float4*)(row + 4);
    uint4 wq;
    wq.x = pack2bf(f0.x, f0.y);
    wq.y = pack2bf(f0.z, f0.w);
    wq.z = pack2bf(f1.x, f1.y);
    wq.w = pack2bf(f1.z, f1.w);
    WihF[i] = wq;
  } else if (idx < 81920) {                // W_out transpose (fp32)
    int i = idx - 49152;
    int o4 = (i & 63) * 4;
    int k = i >> 6;
    float4 v;
    v.x = Wout[(size_t)(o4 + 0) * NH + k];
    v.y = Wout[(size_t)(o4 + 1) * NH + k];
    v.z = Wout[(size_t)(o4 + 2) * NH + k];
    v.w = Wout[(size_t)(o4 + 3) * NH + k];
    *(float4*)&WoT[(size_t)k * NO + o4] = v;
  } else if (idx < 82432) {                // bias sum
    int n = idx - 81920;
    BS[n] = bih[n] + bhh[n];
  }
}

// ---------- kernel 1: x_proj GEMM, B register-stationary with m-reuse ----------
__device__ __forceinline__ void ld_pack(uint4 (&af)[8], const float* __restrict__ A,
                                        int mt, int sl, int quad) {
  const float* ar = A + (size_t)(mt * 16 + sl) * NI + quad * 8;
#pragma unroll
  for (int k0 = 0; k0 < 8; ++k0) {
    float4 f0 = *(const float4*)(ar + k0 * 32);
    float4 f1 = *(const float4*)(ar + k0 * 32 + 4);
    uint4 ap;
    ap.x = pack2bf(f0.x, f0.y);
    ap.y = pack2bf(f0.z, f0.w);
    ap.z = pack2bf(f1.x, f1.y);
    ap.w = pack2bf(f1.z, f1.w);
    af[k0] = ap;
  }
}

__device__ __forceinline__ void do_tile(const uint4 (&af)[8], const uint4 (&Wb)[32],
                                        const float4 (&bs)[4], uint16_t* __restrict__ XP,
                                        int g, int mt, int sl, int quad) {
  f32x4 acc[4] = {};
#pragma unroll
  for (int k0 = 0; k0 < 8; ++k0) {
    bf16x8 a = __builtin_bit_cast(bf16x8, af[k0]);
#pragma unroll
    for (int u = 0; u < 4; ++u) acc[u] = mfma16_ab(Wb[u * 8 + k0], a, acc[u]);
  }
  uint16_t* xrow = XP + (size_t)(mt * 16 + sl) * NH + g * 64 + quad * 4;
#pragma unroll
  for (int u = 0; u < 4; ++u) {
    uint2 pw;
    pw.x = pack2bf(acc[u][0] + bs[u].x, acc[u][1] + bs[u].y);
    pw.y = pack2bf(acc[u][2] + bs[u].z, acc[u][3] + bs[u].w);
    *(uint2*)(xrow + u * 16) = pw;
  }
}

__global__ __launch_bounds__(256, 2) void xproj_kernel(const float* __restrict__ A,
                                                       const uint4* __restrict__ WihF,
                                                       const float* __restrict__ BS,
                                                       uint16_t* __restrict__ XP) {
  const int w = threadIdx.x >> 6;
  const int l = threadIdx.x & 63;
  const int sl = l & 15, quad = l >> 4;
  const int g = blockIdx.y;                     // n-group 0..7 (64 cols)
  const int mt0 = blockIdx.x * 16 + w * 4;      // first of 4 m-tiles for this wave

  uint4 Wb[32];                                 // B-frags, loaded once
#pragma unroll
  for (int u = 0; u < 4; ++u)
#pragma unroll
    for (int k0 = 0; k0 < 8; ++k0)
      Wb[u * 8 + k0] = WihF[(size_t)((g * 4 + u) * 8 + k0) * 64 + l];

  float4 bs[4];
#pragma unroll
  for (int u = 0; u < 4; ++u) bs[u] = *(const float4*)(BS + (g * 4 + u) * 16 + quad * 4);

  uint4 afA[8], afB[8];
  ld_pack(afA, A, mt0 + 0, sl, quad);
  ld_pack(afB, A, mt0 + 1, sl, quad);
  do_tile(afA, Wb, bs, XP, g, mt0 + 0, sl, quad);
  ld_pack(afA, A, mt0 + 2, sl, quad);
  do_tile(afB, Wb, bs, XP, g, mt0 + 1, sl, quad);
  ld_pack(afB, A, mt0 + 3, sl, quad);
  do_tile(afA, Wb, bs, XP, g, mt0 + 2, sl, quad);
  do_tile(afB, Wb, bs, XP, g, mt0 + 3, sl, quad);
}

// ---------- kernel 2: recurrence via MFMA (A-replication), 1 barrier/step ----------
// R8 base (736 us proven: 512 thr, launch_bounds(512,2), xpj prefetch).
// ONE change: W split 52 reg / 12 LDS  ->  56 reg / 8 LDS.
// AGPR budget: 56 quads * 4 + 16 acc = 240 <= 256 cap (R1's 64-quad attempt
// needed 272 -> scratch; 56 stays inside).  Cuts the WL LDS stream from
// 96 KB/step (~1150 cyc LDS pipe) to 64 KB/step (~770 cyc) — the LDS pipe
// (~1700 cyc: WL + h-broadcasts) is the largest per-step pipe in the R8
// counters (MfmaUtil 31% ~ 1070 cyc, VALU 10% ~ 355 cyc).
__global__ __launch_bounds__(512, 2) void recur_kernel(const uint4* __restrict__ WB,
                                                       const float* __restrict__ WoT,
                                                       const uint16_t* __restrict__ XP,
                                                       const float* __restrict__ h0,
                                                       const float* __restrict__ bout,
                                                       float* __restrict__ out) {
  __shared__ uint4 WL[8][512];                   // 64 KB: quads q=56..63
  __shared__ __align__(16) uint16_t h2[2][NH];   // 2 KB: bf16 h, double-buffered
  __shared__ float hsf[NH];                      // 2 KB: fp32 h for readout
  const int t = threadIdx.x;
  const int b = blockIdx.x;
  const int w = t >> 6;
  const int sl = t & 15, quad = (t >> 4) & 3;
  const int myn = w * 64 + quad * 16 + sl;       // h element this lane owns
  const float invT = 1.0f / (float)NT;

  uint4 Wr[56];
#pragma unroll
  for (int q = 0; q < 56; ++q) Wr[q] = WB[q * 512 + t];
#pragma unroll
  for (int i = 0; i < 8; ++i) WL[i][t] = WB[(56 + i) * 512 + t];

  float hj = h0[myn];
  h2[0][myn] = f2bf(hj);
  __syncthreads();

  const uint16_t* xpb = XP + (size_t)b * NT * NH + myn;
  uint16_t xpr = xpb[0];                         // step-0 xproj, prefetched

  for (int ts = 0; ts < NT; ++ts) {
    const int cur = ts & 1;
    // issue NEXT step's xproj load now; consumed one full step (~3400 cyc) later
    const int nts = (ts + 1 < NT) ? (ts + 1) : (NT - 1);
    uint16_t xpn = xpb[(size_t)nts * NH];

    const uint16_t* hbuf = h2[cur];
    f32x4 acc0 = {}, acc1 = {}, acc2 = {}, acc3 = {};
#pragma unroll
    for (int tk = 0; tk < 16; ++tk) {
      bf16x8 hfrag = *(const bf16x8*)(hbuf + tk * 32 + quad * 8);  // quad-broadcast
      acc0 = mfma16(hfrag, Wr[tk], acc0);
      acc1 = mfma16(hfrag, Wr[16 + tk], acc1);
      acc2 = mfma16(hfrag, Wr[32 + tk], acc2);
      uint4 w3 = (tk < 8) ? Wr[48 + tk] : WL[tk - 8][t];
      acc3 = mfma16(hfrag, w3, acc3);
    }
    float y = (quad == 0) ? acc0[0] : (quad == 1) ? acc1[0] : (quad == 2) ? acc2[0] : acc3[0];
    float xpj = __uint_as_float((uint32_t)xpr << 16);
    float hnew = fmaf(fast_tanh(xpj + y), invT, hj);
    hj = hnew;
    h2[cur ^ 1][myn] = f2bf(hnew);
    xpr = xpn;
    __syncthreads();
  }

  hsf[myn] = hj;
  __syncthreads();

  if (t < NO) {
    float c0 = 0.f, c1 = 0.f;
#pragma unroll 4
    for (int k = 0; k < NH; k += 2) {
      c0 = fmaf(WoT[(size_t)k * NO + t], hsf[k], c0);
      c1 = fmaf(WoT[(size_t)(k + 1) * NO + t], hsf[k + 1], c1);
    }
    out[(size_t)b * NO + t] = c0 + c1 + bout[t];
  }
}

// ---------- launch ----------
extern "C" void kernel_launch(void* const* d_in, const int* in_sizes, int n_in,
                              void* d_out, int out_size, void* d_ws, size_t ws_size,
                              hipStream_t stream) {
  const float* inputs = (const float*)d_in[0];
  const float* Wih    = (const float*)d_in[1];
  const float* bih    = (const float*)d_in[2];
  const float* Whh    = (const float*)d_in[3];
  const float* bhh    = (const float*)d_in[4];
  const float* Wout   = (const float*)d_in[5];
  const float* bout   = (const float*)d_in[6];
  const float* h0     = (const float*)d_in[7];
  float* out = (float*)d_out;

  char* ws = (char*)d_ws;
  uint4*    WB   = (uint4*)ws;                          // 512 KB: W_hh B-frags
  float*    WoT  = (float*)(ws + (512u << 10));         // 512 KB: W_out^T
  uint4*    WihF = (uint4*)(ws + (1024u << 10));        // 256 KB: Wih A-frags
  float*    BS   = (float*)(ws + (1280u << 10));        // 2 KB: bias sum
  uint16_t* XP   = (uint16_t*)(ws + (1536u << 10));     // 64 MB: x_proj bf16

  hipLaunchKernelGGL(prep_kernel, dim3(322), dim3(256), 0, stream,
                     Whh, Wih, Wout, bih, bhh, WB, WoT, WihF, BS);
  hipLaunchKernelGGL(xproj_kernel, dim3(NB * NT / 256, 8), dim3(256), 0, stream,
                     inputs, WihF, BS, XP);
  hipLaunchKernelGGL(recur_kernel, dim3(NB), dim3(512), 0, stream,
                     WB, WoT, XP, h0, bout, out);
}

// Round 11
// 827.405 us; speedup vs baseline: 1.1008x; 1.1008x over previous
//
#include <hip/hip_runtime.h>
#include <stdint.h>

#define NB 128   // batch
#define NT 512   // time steps
#define NI 256   // input dim
#define NH 512   // hidden dim
#define NO 256   // output dim

// ---------- bf16 helpers ----------
__device__ __forceinline__ uint16_t f2bf(float x) {
  uint32_t u = __float_as_uint(x);
  return (uint16_t)((u + 0x7fffu + ((u >> 16) & 1u)) >> 16);
}
__device__ __forceinline__ uint32_t pack2bf(float a, float b) {
  return (uint32_t)f2bf(a) | ((uint32_t)f2bf(b) << 16);
}

__device__ __forceinline__ float fast_tanh(float x) {
  float e = __expf(2.0f * x);
#if __has_builtin(__builtin_amdgcn_rcpf)
  return 1.0f - 2.0f * __builtin_amdgcn_rcpf(e + 1.0f);
#else
  return 1.0f - 2.0f / (e + 1.0f);
#endif
}

typedef __bf16 bf16x8 __attribute__((ext_vector_type(8)));
typedef float f32x4 __attribute__((ext_vector_type(4)));

__device__ __forceinline__ f32x4 mfma16(bf16x8 a, uint4 b, f32x4 c) {
  return __builtin_amdgcn_mfma_f32_16x16x32_bf16(a, __builtin_bit_cast(bf16x8, b), c, 0, 0, 0);
}
__device__ __forceinline__ f32x4 mfma16_ab(uint4 a, bf16x8 b, f32x4 c) {
  return __builtin_amdgcn_mfma_f32_16x16x32_bf16(__builtin_bit_cast(bf16x8, a), b, c, 0, 0, 0);
}

// ---------- kernel 0: pack W_hh B-frags; Wih->frag order; transpose W_out; bias sum ----------
// B-frag quad q = u*16 + tk (u=n-tile 0..3, tk=k-tile 0..15):
//   n = (t>>6)*64 + u*16 + (t&15), k = tk*32 + ((t>>4)&3)*8 + j, value W_hh[n][k].
// Stored WB[q*512 + t]. q<52 -> regs, q>=52 -> LDS in recur.
// xproj A-frag WihF[(U*8+k0)*64 + l]: row n=U*16+(l&15), k=k0*32+(l>>4)*8+j.
__global__ __launch_bounds__(256) void prep_kernel(const float* __restrict__ Whh,
                                                   const float* __restrict__ Wih,
                                                   const float* __restrict__ Wout,
                                                   const float* __restrict__ bih,
                                                   const float* __restrict__ bhh,
                                                   uint4* __restrict__ WB,
                                                   float* __restrict__ WoT,
                                                   uint4* __restrict__ WihF,
                                                   float* __restrict__ BS) {
  int idx = blockIdx.x * 256 + threadIdx.x;
  if (idx < 32768) {                       // W_hh B-fragments
    int q = idx >> 9, t = idx & 511;
    int u = q >> 4, tk = q & 15;
    int n = (t >> 6) * 64 + u * 16 + (t & 15);
    int kb = tk * 32 + ((t >> 4) & 3) * 8;
    const float* row = Whh + (size_t)n * NH + kb;
    float4 f0 = *(const float4*)row;
    float4 f1 = *(const float4*)(row + 4);
    uint4 wq;
    wq.x = pack2bf(f0.x, f0.y);
    wq.y = pack2bf(f0.z, f0.w);
    wq.z = pack2bf(f1.x, f1.y);
    wq.w = pack2bf(f1.z, f1.w);
    WB[idx] = wq;
  } else if (idx < 49152) {                // Wih A-fragments (for xproj arg0)
    int i = idx - 32768;
    int l = i & 63;
    int uk = i >> 6;
    int k0 = uk & 7, u = uk >> 3;
    int n = u * 16 + (l & 15);
    int kb = k0 * 32 + (l >> 4) * 8;
    const float* row = Wih + (size_t)n * NI + kb;
    float4 f0 = *(const float4*)row;
    float4 f1 = *(const float4*)(row + 4);
    uint4 wq;
    wq.x = pack2bf(f0.x, f0.y);
    wq.y = pack2bf(f0.z, f0.w);
    wq.z = pack2bf(f1.x, f1.y);
    wq.w = pack2bf(f1.z, f1.w);
    WihF[i] = wq;
  } else if (idx < 81920) {                // W_out transpose (fp32)
    int i = idx - 49152;
    int o4 = (i & 63) * 4;
    int k = i >> 6;
    float4 v;
    v.x = Wout[(size_t)(o4 + 0) * NH + k];
    v.y = Wout[(size_t)(o4 + 1) * NH + k];
    v.z = Wout[(size_t)(o4 + 2) * NH + k];
    v.w = Wout[(size_t)(o4 + 3) * NH + k];
    *(float4*)&WoT[(size_t)k * NO + o4] = v;
  } else if (idx < 82432) {                // bias sum
    int n = idx - 81920;
    BS[n] = bih[n] + bhh[n];
  }
}

// ---------- kernel 1: x_proj GEMM, A-STATIONARY ----------
// R9 analysis: the old (256 m-chunks x 8 n-groups) grid re-read each A-tile
// from HBM up to 8x (per-XCD concurrent working set 8 MB > 4 MB L2) ->
// ~60-80 us of the ~120 us xproj time.  Now: each wave loads its 2 m-tiles'
// A-frags ONCE into regs (16 quads), then loops all 8 n-groups x 4 n-tiles,
// double-buffering 8 weight quads + bias from L2-resident WihF/BS.
// A is read from HBM exactly once (64 MB).  ~150 VGPR, no LDS, no barriers.
// Per-output MFMA chain identical to before (k0 ascending) -> bit-identical XP.
__device__ __forceinline__ void ld_pack(uint4 (&af)[8], const float* __restrict__ A,
                                        int mt, int sl, int quad) {
  const float* ar = A + (size_t)(mt * 16 + sl) * NI + quad * 8;
#pragma unroll
  for (int k0 = 0; k0 < 8; ++k0) {
    float4 f0 = *(const float4*)(ar + k0 * 32);
    float4 f1 = *(const float4*)(ar + k0 * 32 + 4);
    uint4 ap;
    ap.x = pack2bf(f0.x, f0.y);
    ap.y = pack2bf(f0.z, f0.w);
    ap.z = pack2bf(f1.x, f1.y);
    ap.w = pack2bf(f1.z, f1.w);
    af[k0] = ap;
  }
}

__device__ __forceinline__ void ld_w(uint4 (&Wc)[8], float4& bsv,
                                     const uint4* __restrict__ WihF,
                                     const float* __restrict__ BS,
                                     int gu, int l, int quad) {
  const int U = gu >> 2 << 2 | (gu & 3);        // U = g*4+u == gu
#pragma unroll
  for (int k0 = 0; k0 < 8; ++k0) Wc[k0] = WihF[(size_t)(gu * 8 + k0) * 64 + l];
  bsv = *(const float4*)(BS + U * 16 + quad * 4);
}

__device__ __forceinline__ void do_gu(const uint4 (&Wc)[8], const float4 bsv,
                                      const uint4 (&afA)[8], const uint4 (&afB)[8],
                                      uint16_t* __restrict__ XP,
                                      int gu, int mt0, int sl, int quad) {
  const int g = gu >> 2, u = gu & 3;
  f32x4 a0 = {}, a1 = {};
#pragma unroll
  for (int k0 = 0; k0 < 8; ++k0) {
    a0 = mfma16_ab(Wc[k0], __builtin_bit_cast(bf16x8, afA[k0]), a0);
    a1 = mfma16_ab(Wc[k0], __builtin_bit_cast(bf16x8, afB[k0]), a1);
  }
  const size_t col = (size_t)(g * 64 + quad * 4 + u * 16);
  uint2 p0, p1;
  p0.x = pack2bf(a0[0] + bsv.x, a0[1] + bsv.y);
  p0.y = pack2bf(a0[2] + bsv.z, a0[3] + bsv.w);
  p1.x = pack2bf(a1[0] + bsv.x, a1[1] + bsv.y);
  p1.y = pack2bf(a1[2] + bsv.z, a1[3] + bsv.w);
  *(uint2*)(XP + (size_t)(mt0 * 16 + sl) * NH + col) = p0;
  *(uint2*)(XP + (size_t)((mt0 + 1) * 16 + sl) * NH + col) = p1;
}

__global__ __launch_bounds__(256, 2) void xproj_kernel(const float* __restrict__ A,
                                                       const uint4* __restrict__ WihF,
                                                       const float* __restrict__ BS,
                                                       uint16_t* __restrict__ XP) {
  const int w = threadIdx.x >> 6;
  const int l = threadIdx.x & 63;
  const int sl = l & 15, quad = l >> 4;
  const int mt0 = blockIdx.x * 8 + w * 2;       // this wave's 2 m-tiles

  uint4 afA[8], afB[8];                          // A-frags, loaded ONCE
  ld_pack(afA, A, mt0 + 0, sl, quad);
  ld_pack(afB, A, mt0 + 1, sl, quad);

  uint4 WcA[8], WcB[8];                          // double-buffered weight quads
  float4 bsA, bsB;
  ld_w(WcA, bsA, WihF, BS, 0, l, quad);
#pragma unroll 1
  for (int gu = 0; gu < 32; gu += 2) {
    ld_w(WcB, bsB, WihF, BS, gu + 1, l, quad);
    do_gu(WcA, bsA, afA, afB, XP, gu, mt0, sl, quad);
    if (gu + 2 < 32) ld_w(WcA, bsA, WihF, BS, gu + 2, l, quad);
    do_gu(WcB, bsB, afA, afB, XP, gu + 1, mt0, sl, quad);
  }
}

// ---------- kernel 2: recurrence via MFMA (A-replication), 1 barrier/step ----------
// EXACT R8 kernel (736 us proven best: 512 thr, launch_bounds(512,2),
// 52 AGPR quads + 12 LDS quads, xpj prefetched one step ahead).  R9 proved
// 56/8 tips the allocator (WRITE_SIZE 640->1152 KB, +37 us) — do not touch.
__global__ __launch_bounds__(512, 2) void recur_kernel(const uint4* __restrict__ WB,
                                                       const float* __restrict__ WoT,
                                                       const uint16_t* __restrict__ XP,
                                                       const float* __restrict__ h0,
                                                       const float* __restrict__ bout,
                                                       float* __restrict__ out) {
  __shared__ uint4 WL[12][512];                  // 96 KB: quads q=52..63
  __shared__ __align__(16) uint16_t h2[2][NH];   // 2 KB: bf16 h, double-buffered
  __shared__ float hsf[NH];                      // 2 KB: fp32 h for readout
  const int t = threadIdx.x;
  const int b = blockIdx.x;
  const int w = t >> 6;
  const int sl = t & 15, quad = (t >> 4) & 3;
  const int myn = w * 64 + quad * 16 + sl;       // h element this lane owns
  const float invT = 1.0f / (float)NT;

  uint4 Wr[52];
#pragma unroll
  for (int q = 0; q < 52; ++q) Wr[q] = WB[q * 512 + t];
#pragma unroll
  for (int i = 0; i < 12; ++i) WL[i][t] = WB[(52 + i) * 512 + t];

  float hj = h0[myn];
  h2[0][myn] = f2bf(hj);
  __syncthreads();

  const uint16_t* xpb = XP + (size_t)b * NT * NH + myn;
  uint16_t xpr = xpb[0];                         // step-0 xproj, prefetched

  for (int ts = 0; ts < NT; ++ts) {
    const int cur = ts & 1;
    // issue NEXT step's xproj load now; consumed one full step (~3400 cyc) later
    const int nts = (ts + 1 < NT) ? (ts + 1) : (NT - 1);
    uint16_t xpn = xpb[(size_t)nts * NH];

    const uint16_t* hbuf = h2[cur];
    f32x4 acc0 = {}, acc1 = {}, acc2 = {}, acc3 = {};
#pragma unroll
    for (int tk = 0; tk < 16; ++tk) {
      bf16x8 hfrag = *(const bf16x8*)(hbuf + tk * 32 + quad * 8);  // quad-broadcast
      acc0 = mfma16(hfrag, Wr[tk], acc0);
      acc1 = mfma16(hfrag, Wr[16 + tk], acc1);
      acc2 = mfma16(hfrag, Wr[32 + tk], acc2);
      uint4 w3 = (tk < 4) ? Wr[48 + tk] : WL[tk - 4][t];
      acc3 = mfma16(hfrag, w3, acc3);
    }
    float y = (quad == 0) ? acc0[0] : (quad == 1) ? acc1[0] : (quad == 2) ? acc2[0] : acc3[0];
    float xpj = __uint_as_float((uint32_t)xpr << 16);
    float hnew = fmaf(fast_tanh(xpj + y), invT, hj);
    hj = hnew;
    h2[cur ^ 1][myn] = f2bf(hnew);
    xpr = xpn;
    __syncthreads();
  }

  hsf[myn] = hj;
  __syncthreads();

  if (t < NO) {
    float c0 = 0.f, c1 = 0.f;
#pragma unroll 4
    for (int k = 0; k < NH; k += 2) {
      c0 = fmaf(WoT[(size_t)k * NO + t], hsf[k], c0);
      c1 = fmaf(WoT[(size_t)(k + 1) * NO + t], hsf[k + 1], c1);
    }
    out[(size_t)b * NO + t] = c0 + c1 + bout[t];
  }
}

// ---------- launch ----------
extern "C" void kernel_launch(void* const* d_in, const int* in_sizes, int n_in,
                              void* d_out, int out_size, void* d_ws, size_t ws_size,
                              hipStream_t stream) {
  const float* inputs = (const float*)d_in[0];
  const float* Wih    = (const float*)d_in[1];
  const float* bih    = (const float*)d_in[2];
  const float* Whh    = (const float*)d_in[3];
  const float* bhh    = (const float*)d_in[4];
  const float* Wout   = (const float*)d_in[5];
  const float* bout   = (const float*)d_in[6];
  const float* h0     = (const float*)d_in[7];
  float* out = (float*)d_out;

  char* ws = (char*)d_ws;
  uint4*    WB   = (uint4*)ws;                          // 512 KB: W_hh B-frags
  float*    WoT  = (float*)(ws + (512u << 10));         // 512 KB: W_out^T
  uint4*    WihF = (uint4*)(ws + (1024u << 10));        // 256 KB: Wih A-frags
  float*    BS   = (float*)(ws + (1280u << 10));        // 2 KB: bias sum
  uint16_t* XP   = (uint16_t*)(ws + (1536u << 10));     // 64 MB: x_proj bf16

  hipLaunchKernelGGL(prep_kernel, dim3(322), dim3(256), 0, stream,
                     Whh, Wih, Wout, bih, bhh, WB, WoT, WihF, BS);
  hipLaunchKernelGGL(xproj_kernel, dim3(512), dim3(256), 0, stream,
                     inputs, WihF, BS, XP);
  hipLaunchKernelGGL(recur_kernel, dim3(NB), dim3(512), 0, stream,
                     WB, WoT, XP, h0, bout, out);
}

// Round 12
// 822.477 us; speedup vs baseline: 1.1074x; 1.0060x over previous
//
#include <hip/hip_runtime.h>
#include <stdint.h>

#define NB 128   // batch
#define NT 512   // time steps
#define NI 256   // input dim
#define NH 512   // hidden dim
#define NO 256   // output dim

// ---------- bf16 helpers ----------
__device__ __forceinline__ uint16_t f2bf(float x) {
  uint32_t u = __float_as_uint(x);
  return (uint16_t)((u + 0x7fffu + ((u >> 16) & 1u)) >> 16);
}
__device__ __forceinline__ uint32_t pack2bf(float a, float b) {
  return (uint32_t)f2bf(a) | ((uint32_t)f2bf(b) << 16);
}

__device__ __forceinline__ float fast_tanh(float x) {
  float e = __expf(2.0f * x);
#if __has_builtin(__builtin_amdgcn_rcpf)
  return 1.0f - 2.0f * __builtin_amdgcn_rcpf(e + 1.0f);
#else
  return 1.0f - 2.0f / (e + 1.0f);
#endif
}

typedef __bf16 bf16x8 __attribute__((ext_vector_type(8)));
typedef float f32x4 __attribute__((ext_vector_type(4)));

__device__ __forceinline__ f32x4 mfma16(bf16x8 a, uint4 b, f32x4 c) {
  return __builtin_amdgcn_mfma_f32_16x16x32_bf16(a, __builtin_bit_cast(bf16x8, b), c, 0, 0, 0);
}
__device__ __forceinline__ f32x4 mfma16_ab(uint4 a, bf16x8 b, f32x4 c) {
  return __builtin_amdgcn_mfma_f32_16x16x32_bf16(__builtin_bit_cast(bf16x8, a), b, c, 0, 0, 0);
}

// ---------- kernel 0: pack W_hh B-frags; Wih->frag order; transpose W_out; bias sum ----------
// B-frag quad q = u*16 + tk (u=n-tile 0..3, tk=k-tile 0..15):
//   n = (t>>6)*64 + u*16 + (t&15), k = tk*32 + ((t>>4)&3)*8 + j, value W_hh[n][k].
// Stored WB[q*512 + t]. q<52 -> regs, q>=52 -> LDS in recur.
// xproj A-frag WihF[(U*8+k0)*64 + l]: row n=U*16+(l&15), k=k0*32+(l>>4)*8+j.
__global__ __launch_bounds__(256) void prep_kernel(const float* __restrict__ Whh,
                                                   const float* __restrict__ Wih,
                                                   const float* __restrict__ Wout,
                                                   const float* __restrict__ bih,
                                                   const float* __restrict__ bhh,
                                                   uint4* __restrict__ WB,
                                                   float* __restrict__ WoT,
                                                   uint4* __restrict__ WihF,
                                                   float* __restrict__ BS) {
  int idx = blockIdx.x * 256 + threadIdx.x;
  if (idx < 32768) {                       // W_hh B-fragments
    int q = idx >> 9, t = idx & 511;
    int u = q >> 4, tk = q & 15;
    int n = (t >> 6) * 64 + u * 16 + (t & 15);
    int kb = tk * 32 + ((t >> 4) & 3) * 8;
    const float* row = Whh + (size_t)n * NH + kb;
    float4 f0 = *(const float4*)row;
    float4 f1 = *(const float4*)(row + 4);
    uint4 wq;
    wq.x = pack2bf(f0.x, f0.y);
    wq.y = pack2bf(f0.z, f0.w);
    wq.z = pack2bf(f1.x, f1.y);
    wq.w = pack2bf(f1.z, f1.w);
    WB[idx] = wq;
  } else if (idx < 49152) {                // Wih A-fragments (for xproj arg0)
    int i = idx - 32768;
    int l = i & 63;
    int uk = i >> 6;
    int k0 = uk & 7, u = uk >> 3;
    int n = u * 16 + (l & 15);
    int kb = k0 * 32 + (l >> 4) * 8;
    const float* row = Wih + (size_t)n * NI + kb;
    float4 f0 = *(const float4*)row;
    float4 f1 = *(const float4*)(row + 4);
    uint4 wq;
    wq.x = pack2bf(f0.x, f0.y);
    wq.y = pack2bf(f0.z, f0.w);
    wq.z = pack2bf(f1.x, f1.y);
    wq.w = pack2bf(f1.z, f1.w);
    WihF[i] = wq;
  } else if (idx < 81920) {                // W_out transpose (fp32)
    int i = idx - 49152;
    int o4 = (i & 63) * 4;
    int k = i >> 6;
    float4 v;
    v.x = Wout[(size_t)(o4 + 0) * NH + k];
    v.y = Wout[(size_t)(o4 + 1) * NH + k];
    v.z = Wout[(size_t)(o4 + 2) * NH + k];
    v.w = Wout[(size_t)(o4 + 3) * NH + k];
    *(float4*)&WoT[(size_t)k * NO + o4] = v;
  } else if (idx < 82432) {                // bias sum
    int n = idx - 81920;
    BS[n] = bih[n] + bhh[n];
  }
}

// ---------- kernel 1: x_proj GEMM, A-STATIONARY (R11 proven: ~85 us) ----------
__device__ __forceinline__ void ld_pack(uint4 (&af)[8], const float* __restrict__ A,
                                        int mt, int sl, int quad) {
  const float* ar = A + (size_t)(mt * 16 + sl) * NI + quad * 8;
#pragma unroll
  for (int k0 = 0; k0 < 8; ++k0) {
    float4 f0 = *(const float4*)(ar + k0 * 32);
    float4 f1 = *(const float4*)(ar + k0 * 32 + 4);
    uint4 ap;
    ap.x = pack2bf(f0.x, f0.y);
    ap.y = pack2bf(f0.z, f0.w);
    ap.z = pack2bf(f1.x, f1.y);
    ap.w = pack2bf(f1.z, f1.w);
    af[k0] = ap;
  }
}

__device__ __forceinline__ void ld_w(uint4 (&Wc)[8], float4& bsv,
                                     const uint4* __restrict__ WihF,
                                     const float* __restrict__ BS,
                                     int gu, int l, int quad) {
  const int U = gu >> 2 << 2 | (gu & 3);        // U = g*4+u == gu
#pragma unroll
  for (int k0 = 0; k0 < 8; ++k0) Wc[k0] = WihF[(size_t)(gu * 8 + k0) * 64 + l];
  bsv = *(const float4*)(BS + U * 16 + quad * 4);
}

__device__ __forceinline__ void do_gu(const uint4 (&Wc)[8], const float4 bsv,
                                      const uint4 (&afA)[8], const uint4 (&afB)[8],
                                      uint16_t* __restrict__ XP,
                                      int gu, int mt0, int sl, int quad) {
  const int g = gu >> 2, u = gu & 3;
  f32x4 a0 = {}, a1 = {};
#pragma unroll
  for (int k0 = 0; k0 < 8; ++k0) {
    a0 = mfma16_ab(Wc[k0], __builtin_bit_cast(bf16x8, afA[k0]), a0);
    a1 = mfma16_ab(Wc[k0], __builtin_bit_cast(bf16x8, afB[k0]), a1);
  }
  const size_t col = (size_t)(g * 64 + quad * 4 + u * 16);
  uint2 p0, p1;
  p0.x = pack2bf(a0[0] + bsv.x, a0[1] + bsv.y);
  p0.y = pack2bf(a0[2] + bsv.z, a0[3] + bsv.w);
  p1.x = pack2bf(a1[0] + bsv.x, a1[1] + bsv.y);
  p1.y = pack2bf(a1[2] + bsv.z, a1[3] + bsv.w);
  *(uint2*)(XP + (size_t)(mt0 * 16 + sl) * NH + col) = p0;
  *(uint2*)(XP + (size_t)((mt0 + 1) * 16 + sl) * NH + col) = p1;
}

__global__ __launch_bounds__(256, 2) void xproj_kernel(const float* __restrict__ A,
                                                       const uint4* __restrict__ WihF,
                                                       const float* __restrict__ BS,
                                                       uint16_t* __restrict__ XP) {
  const int w = threadIdx.x >> 6;
  const int l = threadIdx.x & 63;
  const int sl = l & 15, quad = l >> 4;
  const int mt0 = blockIdx.x * 8 + w * 2;       // this wave's 2 m-tiles

  uint4 afA[8], afB[8];                          // A-frags, loaded ONCE
  ld_pack(afA, A, mt0 + 0, sl, quad);
  ld_pack(afB, A, mt0 + 1, sl, quad);

  uint4 WcA[8], WcB[8];                          // double-buffered weight quads
  float4 bsA, bsB;
  ld_w(WcA, bsA, WihF, BS, 0, l, quad);
#pragma unroll 1
  for (int gu = 0; gu < 32; gu += 2) {
    ld_w(WcB, bsB, WihF, BS, gu + 1, l, quad);
    do_gu(WcA, bsA, afA, afB, XP, gu, mt0, sl, quad);
    if (gu + 2 < 32) ld_w(WcA, bsA, WihF, BS, gu + 2, l, quad);
    do_gu(WcB, bsB, afA, afB, XP, gu + 1, mt0, sl, quad);
  }
}

// ---------- kernel 2: recurrence via MFMA (A-replication), 1 barrier/step ----------
// R8/R11 base (730 us), ONE change: the xpj prefetch ISSUE POINT is pinned at
// the step top with asm volatile (compiler was free to SINK the C-level load
// toward its use at step end; then the mandatory s_waitcnt vmcnt(0) before
// s_barrier exposed most of the ~900 cyc HBM latency EVERY step).  Volatile
// asm cannot be sunk; by the barrier drain the load has had ~3000 cyc.
// Consumption goes through a tied s_waitcnt asm ("+v" orders the copy after
// the wait — rule: compiler may hoist register ops past plain asm waitcnt).
__global__ __launch_bounds__(512, 2) void recur_kernel(const uint4* __restrict__ WB,
                                                       const float* __restrict__ WoT,
                                                       const uint16_t* __restrict__ XP,
                                                       const float* __restrict__ h0,
                                                       const float* __restrict__ bout,
                                                       float* __restrict__ out) {
  __shared__ uint4 WL[12][512];                  // 96 KB: quads q=52..63
  __shared__ __align__(16) uint16_t h2[2][NH];   // 2 KB: bf16 h, double-buffered
  __shared__ float hsf[NH];                      // 2 KB: fp32 h for readout
  const int t = threadIdx.x;
  const int b = blockIdx.x;
  const int w = t >> 6;
  const int sl = t & 15, quad = (t >> 4) & 3;
  const int myn = w * 64 + quad * 16 + sl;       // h element this lane owns
  const float invT = 1.0f / (float)NT;

  uint4 Wr[52];
#pragma unroll
  for (int q = 0; q < 52; ++q) Wr[q] = WB[q * 512 + t];
#pragma unroll
  for (int i = 0; i < 12; ++i) WL[i][t] = WB[(52 + i) * 512 + t];

  float hj = h0[myn];
  h2[0][myn] = f2bf(hj);
  __syncthreads();

  const uint16_t* xpb = XP + (size_t)b * NT * NH + myn;
  uint16_t xpr = xpb[0];                         // step-0 xproj, prefetched

  for (int ts = 0; ts < NT; ++ts) {
    const int cur = ts & 1;
    // Pin the NEXT step's xproj load issue HERE (cannot be sunk).
    const int nts = (ts + 1 < NT) ? (ts + 1) : (NT - 1);
    const uint16_t* xpp = xpb + (size_t)nts * NH;
    uint32_t xpn_r;
    asm volatile("global_load_ushort %0, %1, off" : "=v"(xpn_r) : "v"(xpp));

    const uint16_t* hbuf = h2[cur];
    f32x4 acc0 = {}, acc1 = {}, acc2 = {}, acc3 = {};
#pragma unroll
    for (int tk = 0; tk < 16; ++tk) {
      bf16x8 hfrag = *(const bf16x8*)(hbuf + tk * 32 + quad * 8);  // quad-broadcast
      acc0 = mfma16(hfrag, Wr[tk], acc0);
      acc1 = mfma16(hfrag, Wr[16 + tk], acc1);
      acc2 = mfma16(hfrag, Wr[32 + tk], acc2);
      uint4 w3 = (tk < 4) ? Wr[48 + tk] : WL[tk - 4][t];
      acc3 = mfma16(hfrag, w3, acc3);
    }
    float y = (quad == 0) ? acc0[0] : (quad == 1) ? acc1[0] : (quad == 2) ? acc2[0] : acc3[0];
    float xpj = __uint_as_float((uint32_t)xpr << 16);
    float hnew = fmaf(fast_tanh(xpj + y), invT, hj);
    hj = hnew;
    h2[cur ^ 1][myn] = f2bf(hnew);
    // Wait for the prefetch (~3000 cyc after issue -> ~free), then consume.
    asm volatile("s_waitcnt vmcnt(0)" : "+v"(xpn_r) :: "memory");
    xpr = (uint16_t)xpn_r;
    __syncthreads();
  }

  hsf[myn] = hj;
  __syncthreads();

  if (t < NO) {
    float c0 = 0.f, c1 = 0.f;
#pragma unroll 4
    for (int k = 0; k < NH; k += 2) {
      c0 = fmaf(WoT[(size_t)k * NO + t], hsf[k], c0);
      c1 = fmaf(WoT[(size_t)(k + 1) * NO + t], hsf[k + 1], c1);
    }
    out[(size_t)b * NO + t] = c0 + c1 + bout[t];
  }
}

// ---------- launch ----------
extern "C" void kernel_launch(void* const* d_in, const int* in_sizes, int n_in,
                              void* d_out, int out_size, void* d_ws, size_t ws_size,
                              hipStream_t stream) {
  const float* inputs = (const float*)d_in[0];
  const float* Wih    = (const float*)d_in[1];
  const float* bih    = (const float*)d_in[2];
  const float* Whh    = (const float*)d_in[3];
  const float* bhh    = (const float*)d_in[4];
  const float* Wout   = (const float*)d_in[5];
  const float* bout   = (const float*)d_in[6];
  const float* h0     = (const float*)d_in[7];
  float* out = (float*)d_out;

  char* ws = (char*)d_ws;
  uint4*    WB   = (uint4*)ws;                          // 512 KB: W_hh B-frags
  float*    WoT  = (float*)(ws + (512u << 10));         // 512 KB: W_out^T
  uint4*    WihF = (uint4*)(ws + (1024u << 10));        // 256 KB: Wih A-frags
  float*    BS   = (float*)(ws + (1280u << 10));        // 2 KB: bias sum
  uint16_t* XP   = (uint16_t*)(ws + (1536u << 10));     // 64 MB: x_proj bf16

  hipLaunchKernelGGL(prep_kernel, dim3(322), dim3(256), 0, stream,
                     Whh, Wih, Wout, bih, bhh, WB, WoT, WihF, BS);
  hipLaunchKernelGGL(xproj_kernel, dim3(512), dim3(256), 0, stream,
                     inputs, WihF, BS, XP);
  hipLaunchKernelGGL(recur_kernel, dim3(NB), dim3(512), 0, stream,
                     WB, WoT, XP, h0, bout, out);
}